// Round 7
// baseline (52030.646 us; speedup 1.0000x reference)
//
#include <hip/hip_runtime.h>
#include <math.h>

#define NV    8192
#define DEG   16
#define EMBD  512
#define NPCC  256
#define NL    257
#define GBLK  32
#define TPB   256
#define K     10

// workspace layout (bytes)
#define WS_FLAG  0        // 32 flags, 128B apart (4 KB)
#define WS_SSQ   4096     // 4*32 floats
#define WS_OHD   5120     // 256 floats
#define WS_H1    8192     // ring2 x K x 512 floats (40960 B)
#define WS_H2    49152    // ring2 x K x 512 floats (40960 B)
#define WS_LOG   90112    // ring2 x K x 260 floats (20800 B)
#define WS_EHP   110912   // ring64 x 32 floats (8192 B)
#define WS_EHV   119104   // 8192 floats (32768 B)
#define WS_HF    152064   // 8192*512 floats = 16 MB

struct __align__(16) Smem {
  float wembT[16*512];   // W[:, kslice] transposed: [out][in]
  float fc1[16*512];
  float fc2[13*512];     // padded rows zero
  float fc3[9*512];      // padded rows/cols zero
  float ohdot[256];
  float a2[512];
  float newe8[K][512];
  float logits[K*260];   // staged D-batch logits
  float e[K][20];
  float attn[K][20];
  float hev[K][16];
  float bpv[K];
  int   biv[K];
  float fc1b[16];
  float fc2b[16];
  float fc3b[16];
  float red[16];
  float scalf[4];        // 0: lpp, 1: reg
  int   scali[4];        // 0: n_used
  int   nbrs[4][K][16];  // ring by tick&3
  int   bmeta[4][2];     // ring: v0, n
  int   chosen[K];
  int   slotbad[K];
  unsigned char colors[NV];
};
static_assert(sizeof(Smem) <= 160*1024, "LDS overflow");

__device__ __forceinline__ float dot4(const float4 a, const float4 b) {
  return a.x*b.x + a.y*b.y + a.z*b.z + a.w*b.w;
}
__device__ __forceinline__ float red64_add(float x) {
  #pragma unroll
  for (int off = 1; off < 64; off <<= 1) x += __shfl_xor(x, off, 64);
  return x;
}
__device__ __forceinline__ float red16_add(float x) {
  #pragma unroll
  for (int off = 1; off < 16; off <<= 1) x += __shfl_xor(x, off, 64);
  return x;
}

// masked softmax-argmax scan over 257 candidates; arithmetic identical to R5.
__device__ __forceinline__ void d_scan(const unsigned char* colors, const int* nbrsD,
                                       const float* lg, int nused, int lane,
                                       float& bp_out, int& bi_out) {
  int nc[DEG];
  #pragma unroll
  for (int j = 0; j < DEG; ++j) nc[j] = (int)colors[nbrsD[j]] - 1;
  float sv[5]; float bmx = -INFINITY;
  #pragma unroll
  for (int p = 0; p < 5; ++p) {
    int idx = lane + p*64;
    float val = -INFINITY;
    if (idx < NL) {
      val = lg[idx];
      bool msk = (idx >= nused) && (idx < NPCC);
      #pragma unroll
      for (int j = 0; j < DEG; ++j) msk |= (idx == nc[j]);
      if (msk) val = -INFINITY;
    }
    sv[p] = val;
    bmx = fmaxf(bmx, val);
  }
  #pragma unroll
  for (int off = 1; off < 64; off <<= 1) bmx = fmaxf(bmx, __shfl_xor(bmx, off, 64));
  float ssum = 0.f;
  #pragma unroll
  for (int p = 0; p < 5; ++p) ssum += expf(sv[p] - bmx);
  #pragma unroll
  for (int off = 1; off < 64; off <<= 1) ssum += __shfl_xor(ssum, off, 64);
  float bp = -1.f; int bi = NL + 10;
  #pragma unroll
  for (int p = 0; p < 5; ++p) {
    int idx = lane + p*64;
    float pj = (idx < NL) ? (expf(sv[p] - bmx) / ssum) : -1.f;
    if (pj > bp) { bp = pj; bi = idx; }
  }
  #pragma unroll
  for (int off = 1; off < 64; off <<= 1) {
    float op = __shfl_xor(bp, off, 64);
    int   oi = __shfl_xor(bi, off, 64);
    if (op > bp || (op == bp && oi < bi)) { bp = op; bi = oi; }
  }
  bp_out = bp; bi_out = bi;
}

#define GATHER(SS, HV) do {                                                  \
  int _vv = va + (SS);                                                       \
  _Pragma("unroll")                                                          \
  for (int _j = 0; _j < 16; ++_j) {                                          \
    int _u = S.nbrs[tk3][SS][_j];                                            \
    if (_u < _vv) HV[_j] = *(const float2*)&HF[(size_t)_u*EMBD + c0];        \
    else          HV[_j] = make_float2(0.f, 0.f);                            \
  }                                                                          \
} while (0)

#define AGG(SS, HV) do {                                                     \
  float _a0 = 0.f, _a1 = 0.f;                                                \
  _Pragma("unroll")                                                          \
  for (int _j = 0; _j < 16; ++_j) {                                          \
    float _ax = S.attn[SS][_j+1];                                            \
    _a0 += _ax * HV[_j].x; _a1 += _ax * HV[_j].y;                            \
  }                                                                          \
  S.newe8[SS][c0]   = (_a0 > 0.f) ? _a0 : expm1f(_a0);                       \
  S.newe8[SS][c0+1] = (_a1 > 0.f) ? _a1 : expm1f(_a1);                       \
} while (0)

__global__ void __launch_bounds__(TPB, 1)
gc_kernel(const int* __restrict__ adj, const float* __restrict__ W,
          const float* __restrict__ a, const float* __restrict__ fc1w,
          const float* __restrict__ fc1b_g, const float* __restrict__ fc2w,
          const float* __restrict__ fc2b_g, const float* __restrict__ fc3w,
          const float* __restrict__ fc3b_g, const int* __restrict__ basep,
          float* __restrict__ out, unsigned char* __restrict__ ws)
{
  extern __shared__ char smem_raw[];
  Smem& S = *reinterpret_cast<Smem*>(smem_raw);
  const int b    = blockIdx.x;
  const int t    = threadIdx.x;
  const int wave = t >> 6;
  const int lane = t & 63;
  const int g    = lane >> 4;
  const int j16  = lane & 15;

  unsigned* flags = (unsigned*)(ws + WS_FLAG);
  float* ssqP  = (float*)(ws + WS_SSQ);
  float* ohdg  = (float*)(ws + WS_OHD);
  float* h1g   = (float*)(ws + WS_H1);
  float* h2g   = (float*)(ws + WS_H2);
  float* logg  = (float*)(ws + WS_LOG);
  float* eHpg  = (float*)(ws + WS_EHP);
  float* eHvg  = (float*)(ws + WS_EHV);
  float* HF    = (float*)(ws + WS_HF);

  const int kbase  = b * 16;
  const int nrows2 = (b < 16) ? 13 : 12;
  const int base2  = (b < 16) ? 13*b : 208 + 12*(b-16);
  const int nrows3 = (b == 0) ? 9 : 8;
  const int base3  = (b == 0) ? 0 : 8*b + 1;

  // ================= init =================
  for (int i = t; i < EMBD; i += TPB) S.a2[i] = a[EMBD + i];
  for (int i = t; i < 16*512; i += TPB) S.fc1[i] = fc1w[(size_t)kbase*512 + i];
  for (int i = t; i < 13*512; i += TPB) {
    int rr = i >> 9;
    S.fc2[i] = (rr < nrows2) ? fc2w[(size_t)base2*512 + i] : 0.f;
  }
  for (int i = t; i < 9*512; i += TPB) {
    int rr = i >> 9, cc = i & 511;
    S.fc3[i] = (rr < nrows3 && cc < 400) ? fc3w[(size_t)(base3+rr)*400 + cc] : 0.f;
  }
  for (int i = t; i < 512; i += TPB) {
    const float* src = W + (size_t)i*512 + kbase;
    #pragma unroll
    for (int kk = 0; kk < 16; ++kk) S.wembT[kk*512 + i] = src[kk];
  }
  if (t < 16) {
    S.fc1b[t] = fc1b_g[kbase + t];
    S.fc2b[t] = (t < nrows2) ? fc2b_g[base2 + t] : 0.f;
    S.fc3b[t] = (t < nrows3) ? fc3b_g[base3 + t] : 0.f;
  }
  for (int i = t; i < NV/4; i += TPB) ((int*)S.colors)[i] = 0;
  if (t < 8) ((int*)S.bmeta)[t] = 0;
  if (t == 0) {
    S.colors[0] = 1;     // vertex 0: color 0
    S.scali[0] = 1;      // n_used
    S.scalf[0] = 0.f;    // lpp
  }
  // ohdot slice (8 values per block); block 0 also publishes eHval[0]
  {
    #pragma unroll
    for (int rep = 0; rep < 2; ++rep) {
      int c = b*8 + wave*2 + rep;
      const float* wr = W + (size_t)(512 + c)*512;
      float acc = 0.f;
      #pragma unroll
      for (int p = 0; p < 2; ++p) {
        float4 w4 = *(const float4*)&wr[p*256 + lane*4];
        float4 a4 = *(const float4*)&a[EMBD + p*256 + lane*4];
        acc += dot4(w4, a4);
      }
      acc = red64_add(acc);
      if (lane == 0) {
        ohdg[c] = acc;
        if (c == 0) eHvg[0] = acc;   // eH(0) = dot(W_oh[0], a2)
      }
    }
  }
  __syncthreads();
  // HF row 0 = W_oh[0] (this block's slice) straight from global W
  if (t < 16) HF[kbase + t] = W[(size_t)512*512 + kbase + t];
  // sum-of-squares partials for reg
  {
    float s0=0.f, s1=0.f, s2=0.f, s3=0.f;
    for (int i = t; i < 16*512; i += TPB) {
      float x = S.wembT[i]; s0 += x*x;
      x = S.fc1[i]; s1 += x*x;
    }
    for (int i = t; i < 13*512; i += TPB) { float x = S.fc2[i]; s2 += x*x; }
    for (int i = t; i < 9*512; i += TPB)  { float x = S.fc3[i]; s3 += x*x; }
    for (int i = t; i < 4096; i += TPB) {   // W_oh slice from global
      int c = i >> 4, kk = i & 15;
      float x = W[(size_t)(512 + c)*512 + kbase + kk];
      s0 += x*x;
    }
    s0 = red64_add(s0); s1 = red64_add(s1); s2 = red64_add(s2); s3 = red64_add(s3);
    if (lane == 0) { S.red[wave*4+0]=s0; S.red[wave*4+1]=s1; S.red[wave*4+2]=s2; S.red[wave*4+3]=s3; }
    __syncthreads();
    if (t == 0) {
      for (int m = 0; m < 4; ++m)
        ssqP[m*GBLK + b] = S.red[m] + S.red[4+m] + S.red[8+m] + S.red[12+m];
    }
  }
  // ---- init barrier ----
  unsigned ep = 1;
  __syncthreads();
  if (t == 0) __hip_atomic_store(&flags[b*32], ep, __ATOMIC_RELEASE, __HIP_MEMORY_SCOPE_AGENT);
  if (t < 32) {
    while (__hip_atomic_load(&flags[t*32], __ATOMIC_RELAXED, __HIP_MEMORY_SCOPE_AGENT) < ep) { }
  }
  if (t == 0) (void)__hip_atomic_load(&flags[0], __ATOMIC_ACQUIRE, __HIP_MEMORY_SCOPE_AGENT);
  __syncthreads();

  if (t < 256) S.ohdot[t] = ohdg[t];
  if (b == 0 && t == 0) {
    float reg = 0.f;
    for (int m = 0; m < 4; ++m) {
      float s = 0.f;
      for (int bb = 0; bb < GBLK; ++bb) s += ssqP[m*GBLK + bb];
      reg += sqrtf(s);
    }
    S.scalf[1] = reg;
  }
  __syncthreads();

  // ================= batched pipelined main loop =================
  int va = 1, d_done = 0;
  unsigned T = 0;

  #pragma unroll 1
  for (;;) {
    const int tk3  = (int)(T & 3);
    const int idxD = (int)((T+1) & 3);
    const int idxC = (int)((T+2) & 3);
    const int idxB = (int)((T+3) & 3);
    const int v0D = S.bmeta[idxD][0], nD = S.bmeta[idxD][1];
    const int nC  = S.bmeta[idxC][1];
    const int nB  = S.bmeta[idxB][1];
    const bool canA = (va < NV);
    const int Kc = canA ? ((NV - va < K) ? (NV - va) : K) : 0;
    const int parR = (int)((T+1) & 1);
    const int parW = (int)(T & 1);
    const int c0 = 2*t;

    // ---- phase 0: candidate staging + safety + D logits staging ----
    if (t < Kc*DEG) {
      int s = t >> 4, j = t & 15;
      int v = va + s;
      int u = adj[v*DEG + j];
      S.nbrs[tk3][s][j] = u;
      bool bad = false;
      float er = 0.f;
      if (u < v) {
        if (u > d_done) bad = true;
        else { float eh = eHvg[u]; er = (eh >= 0.f) ? eh : 0.2f*eh; }
      }
      S.e[s][j+1] = er;
      unsigned long long bm = __ballot(bad);
      if (j == 0) S.slotbad[s] = (int)((bm >> (((t >> 4) & 3)*16)) & 0xFFFFull);
    }
    if (t < K) S.e[t][0] = 0.f;
    for (int x = t; x < nD*260; x += TPB)
      S.logits[x] = logg[parR*(K*260) + x];
    __syncthreads();   // sync0

    int n = 0;
    while (n < Kc && S.slotbad[n] == 0) ++n;
    if (t == 0) { S.bmeta[tk3][0] = va; S.bmeta[tk3][1] = n; }

    // ---- phase 1: issue xr loads, issue gathers, D-spec (all waves), BC ----
    // B/C jobs over 16 groups; first pass prefetched, overflow pass below
    const int grp = t >> 4;
    const int tot = nB + nC;
    float4 xr[8];
    bool hasJob = (grp < tot);
    bool isB = hasJob && (grp < nB);
    int  s2j = isB ? grp : grp - nB;
    if (hasJob) {
      const float* xp = isB ? (h1g + parR*(K*512) + s2j*512)
                            : (h2g + parR*(K*512) + s2j*512);
      #pragma unroll
      for (int tt = 0; tt < 8; ++tt) xr[tt] = *(const float4*)&xp[j16*4 + tt*64];
    }
    // gather buffers (4-deep pipeline), issue now to overlap phase-1 compute
    float2 g0[16], g1[16], g2[16], g3[16];
    if (n > 0) GATHER(0, g0);
    if (n > 1) GATHER(1, g1);
    if (n > 2) GATHER(2, g2);
    if (n > 3) GATHER(3, g3);
    // ppre prefetch for eH publish (wave0, block 0)
    float ppre[K];
    #pragma unroll
    for (int s2 = 0; s2 < K; ++s2) ppre[s2] = 0.f;
    if (b == 0 && wave == 0 && lane < 32) {
      #pragma unroll
      for (int s2 = 0; s2 < K; ++s2)
        if (s2 < nD) ppre[s2] = eHpg[((v0D+s2)&63)*32 + lane];
    }
    // attn softmax (wave 2)
    if (wave == 2 && lane < n) {
      float m = 0.f;   // includes e[0]=0
      #pragma unroll
      for (int j = 1; j <= DEG; ++j) m = fmaxf(m, S.e[lane][j]);
      float ex[DEG+1]; float ssum = 0.f;
      #pragma unroll
      for (int j = 0; j <= DEG; ++j) { ex[j] = expf(S.e[lane][j] - m); ssum += ex[j]; }
      #pragma unroll
      for (int j = 0; j <= DEG; ++j) S.attn[lane][j] = ex[j] / ssum;
    }
    // D-speculative scans: wave w handles slots w, w+4, w+8 (assume n_used unchanged)
    {
      const int nspec = S.scali[0];
      #pragma unroll
      for (int rep = 0; rep < 3; ++rep) {
        int s2 = wave + rep*4;
        if (s2 < nD) {
          float bp; int bi;
          d_scan(S.colors, S.nbrs[idxD][s2], S.logits + s2*260, nspec, lane, bp, bi);
          if (lane == 0) { S.bpv[s2] = bp; S.biv[s2] = bi; }
        }
      }
    }
    // BC compute: first (prefetched) job, then overflow jobs (tot can be up to 2K=20)
    if (hasJob) {
      const int nr = isB ? nrows2 : nrows3;
      const float* wbase = isB ? S.fc2 : S.fc3;
      const float* bb    = isB ? S.fc2b : S.fc3b;
      for (int r = 0; r < 13; ++r) {
        if (r >= nr) break;
        float acc = 0.f;
        const float* wrow = wbase + r*512;
        #pragma unroll
        for (int tt = 0; tt < 8; ++tt) {
          float4 w4 = *(const float4*)&wrow[j16*4 + tt*64];
          acc += dot4(xr[tt], w4);
        }
        acc = red16_add(acc);
        if (j16 == 0) {
          if (isB) {
            float hvv = acc + bb[r];
            h2g[parW*(K*512) + s2j*512 + base2 + r] = (hvv >= 0.f) ? hvv : 0.01f*hvv;
          } else {
            logg[parW*(K*260) + s2j*260 + base3 + r] = acc + bb[r];
          }
        }
      }
    }
    #pragma unroll 1
    for (int job = grp + 16; job < tot; job += 16) {
      const bool isB2 = (job < nB);
      const int s22 = isB2 ? job : job - nB;
      const float* xp = isB2 ? (h1g + parR*(K*512) + s22*512)
                             : (h2g + parR*(K*512) + s22*512);
      float4 xr2[8];
      #pragma unroll
      for (int tt = 0; tt < 8; ++tt) xr2[tt] = *(const float4*)&xp[j16*4 + tt*64];
      const int nr = isB2 ? nrows2 : nrows3;
      const float* wbase = isB2 ? S.fc2 : S.fc3;
      const float* bb    = isB2 ? S.fc2b : S.fc3b;
      for (int r = 0; r < 13; ++r) {
        if (r >= nr) break;
        float acc = 0.f;
        const float* wrow = wbase + r*512;
        #pragma unroll
        for (int tt = 0; tt < 8; ++tt) {
          float4 w4 = *(const float4*)&wrow[j16*4 + tt*64];
          acc += dot4(xr2[tt], w4);
        }
        acc = red16_add(acc);
        if (j16 == 0) {
          if (isB2) {
            float hvv = acc + bb[r];
            h2g[parW*(K*512) + s22*512 + base2 + r] = (hvv >= 0.f) ? hvv : 0.01f*hvv;
          } else {
            logg[parW*(K*260) + s22*260 + base3 + r] = acc + bb[r];
          }
        }
      }
    }
    __syncthreads();   // sync1 (spec results + attn in LDS)

    // ---- phase 1b: verify + commit D (wave 0) ----
    if (wave == 0 && nD > 0) {
      int nused = S.scali[0];
      const int nspec = nused;
      float lpp = S.scalf[0];
      #pragma unroll 1
      for (int s2 = 0; s2 < nD; ++s2) {
        const int vD = v0D + s2;
        float bp; int bi;
        if (nused == nspec) { bp = S.bpv[s2]; bi = S.biv[s2]; }
        else {
          d_scan(S.colors, S.nbrs[idxD][s2], S.logits + s2*260, nused, lane, bp, bi);
        }
        const int isnew  = (bi == NPCC) ? 1 : 0;
        const int chosen = isnew ? nused : bi;
        nused += isnew;
        lpp += logf(bp + 1e-8f) - logf(1e-8f);
        if (lane == 0) {
          S.colors[vD] = (unsigned char)(chosen + 1);
          S.chosen[s2] = chosen;
        }
        if (b == 0) {
          float pp = (lane < 32) ? ppre[s2] : 0.f;
          #pragma unroll
          for (int off = 1; off < 32; off <<= 1) pp += __shfl_xor(pp, off, 64);
          if (lane == 0) eHvg[vD] = pp + S.ohdot[chosen];
        }
      }
      if (lane == 0) { S.scali[0] = nused; S.scalf[0] = lpp; }
    }
    __syncthreads();   // sync1b (chosen ready)

    // ---- phase 2: W_oh fold (parallel) + pipelined AGG ----
    {
      const bool foldAct = (t < nD*16);
      const int fsp = t >> 4, fj = t & 15;
      float foldOld = 0.f, foldW = 0.f;
      if (foldAct) {
        foldOld = HF[(size_t)(v0D+fsp)*EMBD + kbase + fj];
        foldW   = W[(size_t)(512 + S.chosen[fsp])*512 + kbase + fj];
      }
      if (foldAct) HF[(size_t)(v0D+fsp)*EMBD + kbase + fj] = foldOld + foldW;
      if (n > 0) { AGG(0, g0); if (4 < n) GATHER(4, g0); }
      if (n > 1) { AGG(1, g1); if (5 < n) GATHER(5, g1); }
      if (n > 2) { AGG(2, g2); if (6 < n) GATHER(6, g2); }
      if (n > 3) { AGG(3, g3); if (7 < n) GATHER(7, g3); }
      if (n > 4) { AGG(4, g0); if (8 < n) GATHER(8, g0); }
      if (n > 5) { AGG(5, g1); if (9 < n) GATHER(9, g1); }
      if (n > 6) { AGG(6, g2); }
      if (n > 7) { AGG(7, g3); }
      if (n > 8) { AGG(8, g0); }
      if (n > 9) { AGG(9, g1); }
    }
    __syncthreads();   // sync2

    // ---- phase 3: batched fc1 + He for all n slots ----
    {
      const int r = wave*4 + g;
      float acc1[K], acc2[K];
      #pragma unroll
      for (int s = 0; s < K; ++s) { acc1[s] = 0.f; acc2[s] = 0.f; }
      const float* w1row = S.fc1 + r*512;
      const float* w2row = S.wembT + r*512;
      #pragma unroll
      for (int tt = 0; tt < 8; ++tt) {
        float4 w1 = *(const float4*)&w1row[j16*4 + tt*64];
        float4 w2 = *(const float4*)&w2row[j16*4 + tt*64];
        #pragma unroll
        for (int s = 0; s < K; ++s) {
          if (s < n) {
            float4 x4 = *(const float4*)&S.newe8[s][j16*4 + tt*64];
            acc1[s] += dot4(x4, w1);
            acc2[s] += dot4(x4, w2);
          }
        }
      }
      #pragma unroll
      for (int s = 0; s < K; ++s) {
        if (s < n) {
          float a1r = red16_add(acc1[s]);
          float a2r = red16_add(acc2[s]);
          if (j16 == 0) {
            float hvv = a1r + S.fc1b[r];
            h1g[parW*(K*512) + s*512 + kbase + r] = (hvv >= 0.f) ? hvv : 0.01f*hvv;
            HF[(size_t)(va+s)*EMBD + kbase + r] = a2r;
            S.hev[s][r] = a2r;
          }
        }
      }
    }
    __syncthreads();   // sync3

    // ---- eH partial publish + global barrier ----
    if (t < n) {
      float pp = 0.f;
      #pragma unroll
      for (int kk = 0; kk < 16; ++kk) pp += S.hev[t][kk] * S.a2[kbase + kk];
      eHpg[((va+t)&63)*32 + b] = pp;
    }
    __syncthreads();
    ++ep;
    if (t == 0) __hip_atomic_store(&flags[b*32], ep, __ATOMIC_RELEASE, __HIP_MEMORY_SCOPE_AGENT);
    if (t < 32) {
      while (__hip_atomic_load(&flags[t*32], __ATOMIC_RELAXED, __HIP_MEMORY_SCOPE_AGENT) < ep) { }
    }
    if (t == 0) (void)__hip_atomic_load(&flags[0], __ATOMIC_ACQUIRE, __HIP_MEMORY_SCOPE_AGENT);
    __syncthreads();

    // ---- advance ----
    if (nD > 0) d_done = v0D + nD - 1;
    va += n;
    ++T;
    if (d_done == NV-1) break;
    if (T > 12000u) break;   // safety: fail validation instead of hanging
  }

  // ================= output =================
  if (b == 0) {
    for (int i = t; i < NV; i += TPB) out[i] = (float)((int)S.colors[i] - 1);
    if (t == 0) {
      int bv = basep[0];
      int bl = (bv >= -100000 && bv <= 100000) ? bv : (int)__int_as_float(bv);
      float loss = ((float)(S.scali[0] - bl)) * S.scalf[0] / 8192.0f + 0.05f * S.scalf[1];
      out[NV] = loss;
    }
  }
}

extern "C" void kernel_launch(void* const* d_in, const int* in_sizes, int n_in,
                              void* d_out, int out_size, void* d_ws, size_t ws_size,
                              hipStream_t stream) {
  const int*   adj  = (const int*)d_in[0];
  const float* W    = (const float*)d_in[1];
  const float* av   = (const float*)d_in[2];
  const float* f1w  = (const float*)d_in[3];
  const float* f1b  = (const float*)d_in[4];
  const float* f2w  = (const float*)d_in[5];
  const float* f2b  = (const float*)d_in[6];
  const float* f3w  = (const float*)d_in[7];
  const float* f3b  = (const float*)d_in[8];
  const int*   bas  = (const int*)d_in[9];
  float* out = (float*)d_out;
  unsigned char* ws = (unsigned char*)d_ws;

  // zero barrier flags (workspace is poisoned 0xAA before every launch)
  (void)hipMemsetAsync(d_ws, 0, 8192, stream);
  (void)hipFuncSetAttribute((const void*)gc_kernel,
                      hipFuncAttributeMaxDynamicSharedMemorySize,
                      (int)sizeof(Smem));
  gc_kernel<<<dim3(GBLK), dim3(TPB), sizeof(Smem), stream>>>(
      adj, W, av, f1w, f1b, f2w, f2b, f3w, f3b, bas, out, ws);
}

// Round 8
// 31834.293 us; speedup vs baseline: 1.6344x; 1.6344x over previous
//
#include <hip/hip_runtime.h>
#include <math.h>

#define NV    8192
#define DEG   16
#define EMBD  512
#define NPCC  256
#define NL    257
#define GBLK  32
#define TPB   256
#define K     10

// workspace layout (bytes)
#define WS_FLAG  0        // 32 flags, 128B apart (4 KB)
#define WS_SSQ   4096
#define WS_OHD   5120
#define WS_H1    8192     // ring2 x K x 512 f (40960)
#define WS_H2    49152    // ring2 x K x 512 f (40960)
#define WS_LOG   90112    // ring2 x K x 260 f (20800)
#define WS_NWE   110912   // ring2 x K x 512 f (40960)
#define WS_EHP   151872   // ring64 x 32 f (8192)
#define WS_EHV   160064   // 8192 f (32768)
#define WS_HF    196608   // 8192*512 f = 16 MB

struct __align__(16) Smem {
  float wembT[16*512];   // W[:, kslice] transposed: [out][in]
  float fc1[16*512];
  float fc2[13*512];     // padded rows zero
  float fc3[9*512];      // padded rows/cols zero
  float ohdot[256];
  float a2[512];
  float newe8[K][512];   // full newe of batch T-1 (staged from nweg)
  float logits[K*260];   // staged D-batch logits
  float e[K][20];
  float attn[K][20];
  float hev[K][16];
  float bpv[K];
  int   biv[K];
  float fc1b[16];
  float fc2b[16];
  float fc3b[16];
  float red[16];
  float scalf[4];        // 0: lpp, 1: reg
  int   scali[4];        // 0: n_used
  int   nbrs[8][K][16];  // ring by tick&7
  int   bmeta[8][2];     // ring: v0, n
  int   chosen[K];
  int   slotbad[K];
  unsigned char colors[NV];
};
static_assert(sizeof(Smem) <= 160*1024, "LDS overflow");

__device__ __forceinline__ float dot4(const float4 a, const float4 b) {
  return a.x*b.x + a.y*b.y + a.z*b.z + a.w*b.w;
}
__device__ __forceinline__ float red64_add(float x) {
  #pragma unroll
  for (int off = 1; off < 64; off <<= 1) x += __shfl_xor(x, off, 64);
  return x;
}
__device__ __forceinline__ float red16_add(float x) {
  #pragma unroll
  for (int off = 1; off < 16; off <<= 1) x += __shfl_xor(x, off, 64);
  return x;
}

// masked softmax-argmax scan over 257 candidates; arithmetic identical to R5/R7.
__device__ __forceinline__ void d_scan(const unsigned char* colors, const int* nbrsD,
                                       const float* lg, int nused, int lane,
                                       float& bp_out, int& bi_out) {
  int nc[DEG];
  #pragma unroll
  for (int j = 0; j < DEG; ++j) nc[j] = (int)colors[nbrsD[j]] - 1;
  float sv[5]; float bmx = -INFINITY;
  #pragma unroll
  for (int p = 0; p < 5; ++p) {
    int idx = lane + p*64;
    float val = -INFINITY;
    if (idx < NL) {
      val = lg[idx];
      bool msk = (idx >= nused) && (idx < NPCC);
      #pragma unroll
      for (int j = 0; j < DEG; ++j) msk |= (idx == nc[j]);
      if (msk) val = -INFINITY;
    }
    sv[p] = val;
    bmx = fmaxf(bmx, val);
  }
  #pragma unroll
  for (int off = 1; off < 64; off <<= 1) bmx = fmaxf(bmx, __shfl_xor(bmx, off, 64));
  float ssum = 0.f;
  #pragma unroll
  for (int p = 0; p < 5; ++p) ssum += expf(sv[p] - bmx);
  #pragma unroll
  for (int off = 1; off < 64; off <<= 1) ssum += __shfl_xor(ssum, off, 64);
  float bp = -1.f; int bi = NL + 10;
  #pragma unroll
  for (int p = 0; p < 5; ++p) {
    int idx = lane + p*64;
    float pj = (idx < NL) ? (expf(sv[p] - bmx) / ssum) : -1.f;
    if (pj > bp) { bp = pj; bi = idx; }
  }
  #pragma unroll
  for (int off = 1; off < 64; off <<= 1) {
    float op = __shfl_xor(bp, off, 64);
    int   oi = __shfl_xor(bi, off, 64);
    if (op > bp || (op == bp && oi < bi)) { bp = op; bi = oi; }
  }
  bp_out = bp; bi_out = bi;
}

__global__ void __launch_bounds__(TPB, 1)
gc_kernel(const int* __restrict__ adj, const float* __restrict__ W,
          const float* __restrict__ a, const float* __restrict__ fc1w,
          const float* __restrict__ fc1b_g, const float* __restrict__ fc2w,
          const float* __restrict__ fc2b_g, const float* __restrict__ fc3w,
          const float* __restrict__ fc3b_g, const int* __restrict__ basep,
          float* __restrict__ out, unsigned char* __restrict__ ws)
{
  extern __shared__ char smem_raw[];
  Smem& S = *reinterpret_cast<Smem*>(smem_raw);
  const int b    = blockIdx.x;
  const int t    = threadIdx.x;
  const int wave = t >> 6;
  const int lane = t & 63;
  const int g    = lane >> 4;
  const int j16  = lane & 15;

  unsigned* flags = (unsigned*)(ws + WS_FLAG);
  float* ssqP  = (float*)(ws + WS_SSQ);
  float* ohdg  = (float*)(ws + WS_OHD);
  float* h1g   = (float*)(ws + WS_H1);
  float* h2g   = (float*)(ws + WS_H2);
  float* logg  = (float*)(ws + WS_LOG);
  float* nweg  = (float*)(ws + WS_NWE);
  float* eHpg  = (float*)(ws + WS_EHP);
  float* eHvg  = (float*)(ws + WS_EHV);
  float* HF    = (float*)(ws + WS_HF);

  const int kbase  = b * 16;
  const int nrows2 = (b < 16) ? 13 : 12;
  const int base2  = (b < 16) ? 13*b : 208 + 12*(b-16);
  const int nrows3 = (b == 0) ? 9 : 8;
  const int base3  = (b == 0) ? 0 : 8*b + 1;

  // ================= init =================
  for (int i = t; i < EMBD; i += TPB) S.a2[i] = a[EMBD + i];
  for (int i = t; i < 16*512; i += TPB) S.fc1[i] = fc1w[(size_t)kbase*512 + i];
  for (int i = t; i < 13*512; i += TPB) {
    int rr = i >> 9;
    S.fc2[i] = (rr < nrows2) ? fc2w[(size_t)base2*512 + i] : 0.f;
  }
  for (int i = t; i < 9*512; i += TPB) {
    int rr = i >> 9, cc = i & 511;
    S.fc3[i] = (rr < nrows3 && cc < 400) ? fc3w[(size_t)(base3+rr)*400 + cc] : 0.f;
  }
  for (int i = t; i < 512; i += TPB) {
    const float* src = W + (size_t)i*512 + kbase;
    #pragma unroll
    for (int kk = 0; kk < 16; ++kk) S.wembT[kk*512 + i] = src[kk];
  }
  if (t < 16) {
    S.fc1b[t] = fc1b_g[kbase + t];
    S.fc2b[t] = (t < nrows2) ? fc2b_g[base2 + t] : 0.f;
    S.fc3b[t] = (t < nrows3) ? fc3b_g[base3 + t] : 0.f;
  }
  for (int i = t; i < NV/4; i += TPB) ((int*)S.colors)[i] = 0;
  if (t < 16) ((int*)S.bmeta)[t] = 0;
  if (t == 0) {
    S.colors[0] = 1;     // vertex 0: color 0
    S.scali[0] = 1;      // n_used
    S.scalf[0] = 0.f;    // lpp
  }
  // ohdot slice (8 values per block); block 0 also publishes eHval[0]
  {
    #pragma unroll
    for (int rep = 0; rep < 2; ++rep) {
      int c = b*8 + wave*2 + rep;
      const float* wr = W + (size_t)(512 + c)*512;
      float acc = 0.f;
      #pragma unroll
      for (int p = 0; p < 2; ++p) {
        float4 w4 = *(const float4*)&wr[p*256 + lane*4];
        float4 a4 = *(const float4*)&a[EMBD + p*256 + lane*4];
        acc += dot4(w4, a4);
      }
      acc = red64_add(acc);
      if (lane == 0) {
        ohdg[c] = acc;
        if (c == 0) eHvg[0] = acc;   // eH(0) = dot(W_oh[0], a2)
      }
    }
  }
  __syncthreads();
  // HF row 0 = W_oh[0] (this block's slice) straight from global W
  if (t < 16) HF[kbase + t] = W[(size_t)512*512 + kbase + t];
  // sum-of-squares partials for reg
  {
    float s0=0.f, s1=0.f, s2=0.f, s3=0.f;
    for (int i = t; i < 16*512; i += TPB) {
      float x = S.wembT[i]; s0 += x*x;
      x = S.fc1[i]; s1 += x*x;
    }
    for (int i = t; i < 13*512; i += TPB) { float x = S.fc2[i]; s2 += x*x; }
    for (int i = t; i < 9*512; i += TPB)  { float x = S.fc3[i]; s3 += x*x; }
    for (int i = t; i < 4096; i += TPB) {   // W_oh slice from global
      int c = i >> 4, kk = i & 15;
      float x = W[(size_t)(512 + c)*512 + kbase + kk];
      s0 += x*x;
    }
    s0 = red64_add(s0); s1 = red64_add(s1); s2 = red64_add(s2); s3 = red64_add(s3);
    if (lane == 0) { S.red[wave*4+0]=s0; S.red[wave*4+1]=s1; S.red[wave*4+2]=s2; S.red[wave*4+3]=s3; }
    __syncthreads();
    if (t == 0) {
      for (int m = 0; m < 4; ++m)
        ssqP[m*GBLK + b] = S.red[m] + S.red[4+m] + S.red[8+m] + S.red[12+m];
    }
  }
  // ---- init barrier ----
  unsigned ep = 1;
  __syncthreads();
  if (t == 0) __hip_atomic_store(&flags[b*32], ep, __ATOMIC_RELEASE, __HIP_MEMORY_SCOPE_AGENT);
  if (t < 32) {
    while (__hip_atomic_load(&flags[t*32], __ATOMIC_RELAXED, __HIP_MEMORY_SCOPE_AGENT) < ep) { }
  }
  if (t == 0) (void)__hip_atomic_load(&flags[0], __ATOMIC_ACQUIRE, __HIP_MEMORY_SCOPE_AGENT);
  __syncthreads();

  if (t < 256) S.ohdot[t] = ohdg[t];
  if (b == 0 && t == 0) {
    float reg = 0.f;
    for (int m = 0; m < 4; ++m) {
      float s = 0.f;
      for (int bb = 0; bb < GBLK; ++bb) s += ssqP[m*GBLK + bb];
      reg += sqrtf(s);
    }
    S.scalf[1] = reg;
  }
  __syncthreads();

  // ================= 5-stage pipelined main loop =================
  // tick T: A1(batch T) stage+gather-slice | A2(T-1) fc1+He | B(T-2) fc2
  //         | C(T-3) fc3 | D(T-4) argmax+commit+fold
  int va = 1, d_done = 0;
  unsigned T = 0;

  #pragma unroll 1
  for (;;) {
    const int tk   = (int)(T & 7);
    const int iA2  = (int)((T+7) & 7);
    const int iB   = (int)((T+6) & 7);
    const int iC   = (int)((T+5) & 7);
    const int iD   = (int)((T+4) & 7);
    const int v0A2 = S.bmeta[iA2][0], nA2 = S.bmeta[iA2][1];
    const int nB   = S.bmeta[iB][1];
    const int nC   = S.bmeta[iC][1];
    const int v0D  = S.bmeta[iD][0],  nD  = S.bmeta[iD][1];
    const bool canA = (va < NV);
    const int Kc = canA ? ((NV - va < K) ? (NV - va) : K) : 0;
    const int pT  = (int)(T & 1);
    const int pT1 = pT ^ 1;

    // ---- P0: stage batch + logits + newe-full + BC xr prefetch ----
    if (t < Kc*DEG) {
      int s = t >> 4, j = t & 15;
      int v = va + s;
      int u = adj[v*DEG + j];
      S.nbrs[tk][s][j] = u;
      bool bad = false;
      float er = 0.f;
      if (u < v) {
        if (u > d_done) bad = true;
        else { float eh = eHvg[u]; er = (eh >= 0.f) ? eh : 0.2f*eh; }
      }
      S.e[s][j+1] = er;
      unsigned long long bm = __ballot(bad);
      if (j == 0) S.slotbad[s] = (int)((bm >> (((t >> 4) & 3)*16)) & 0xFFFFull);
    }
    if (t < K) S.e[t][0] = 0.f;
    for (int x = t; x < nD*260; x += TPB)
      S.logits[x] = logg[pT*(K*260) + x];
    for (int x = t; x < nA2*128; x += TPB)
      ((float4*)S.newe8)[x] = ((const float4*)(nweg + pT1*(K*512)))[x];
    // BC xr prefetch (first pass jobs on 16 groups)
    const int grp = t >> 4;
    const int tot = nB + nC;
    float4 xr[8];
    const bool hasJob = (grp < tot);
    const bool isB = hasJob && (grp < nB);
    const int s2j = isB ? grp : grp - nB;
    if (hasJob) {
      const float* xp = isB ? (h1g + pT*(K*512) + s2j*512)
                            : (h2g + pT1*(K*512) + s2j*512);
      #pragma unroll
      for (int tt = 0; tt < 8; ++tt) xr[tt] = *(const float4*)&xp[j16*4 + tt*64];
    }
    __syncthreads();   // sync0

    int n = 0;
    while (n < Kc && S.slotbad[n] == 0) ++n;
    if (t == 0) { S.bmeta[tk][0] = va; S.bmeta[tk][1] = n; }

    // ---- P1: softmax (w2) + D-spec (all waves) + BC compute ----
    if (wave == 2 && lane < n) {
      float m = 0.f;   // includes e[0]=0
      #pragma unroll
      for (int j = 1; j <= DEG; ++j) m = fmaxf(m, S.e[lane][j]);
      float ex[DEG+1]; float ssum = 0.f;
      #pragma unroll
      for (int j = 0; j <= DEG; ++j) { ex[j] = expf(S.e[lane][j] - m); ssum += ex[j]; }
      #pragma unroll
      for (int j = 0; j <= DEG; ++j) S.attn[lane][j] = ex[j] / ssum;
    }
    // ppre prefetch for eH finalize (wave0, block 0)
    float ppre[K];
    #pragma unroll
    for (int s2 = 0; s2 < K; ++s2) ppre[s2] = 0.f;
    if (b == 0 && wave == 0 && lane < 32) {
      #pragma unroll
      for (int s2 = 0; s2 < K; ++s2)
        if (s2 < nD) ppre[s2] = eHpg[((v0D+s2)&63)*32 + lane];
    }
    // D-speculative scans
    {
      const int nspec = S.scali[0];
      #pragma unroll
      for (int rep = 0; rep < 3; ++rep) {
        int s2 = wave + rep*4;
        if (s2 < nD) {
          float bp; int bi;
          d_scan(S.colors, S.nbrs[iD][s2], S.logits + s2*260, nspec, lane, bp, bi);
          if (lane == 0) { S.bpv[s2] = bp; S.biv[s2] = bi; }
        }
      }
    }
    // BC compute (prefetched first pass)
    if (hasJob) {
      const int nr = isB ? nrows2 : nrows3;
      const float* wbase = isB ? S.fc2 : S.fc3;
      const float* bb    = isB ? S.fc2b : S.fc3b;
      for (int r = 0; r < 13; ++r) {
        if (r >= nr) break;
        float acc = 0.f;
        const float* wrow = wbase + r*512;
        #pragma unroll
        for (int tt = 0; tt < 8; ++tt) {
          float4 w4 = *(const float4*)&wrow[j16*4 + tt*64];
          acc += dot4(xr[tt], w4);
        }
        acc = red16_add(acc);
        if (j16 == 0) {
          if (isB) {
            float hvv = acc + bb[r];
            h2g[pT*(K*512) + s2j*512 + base2 + r] = (hvv >= 0.f) ? hvv : 0.01f*hvv;
          } else {
            logg[pT1*(K*260) + s2j*260 + base3 + r] = acc + bb[r];
          }
        }
      }
    }
    #pragma unroll 1
    for (int job = grp + 16; job < tot; job += 16) {
      const bool isB2 = (job < nB);
      const int s22 = isB2 ? job : job - nB;
      const float* xp = isB2 ? (h1g + pT*(K*512) + s22*512)
                             : (h2g + pT1*(K*512) + s22*512);
      float4 xr2[8];
      #pragma unroll
      for (int tt = 0; tt < 8; ++tt) xr2[tt] = *(const float4*)&xp[j16*4 + tt*64];
      const int nr = isB2 ? nrows2 : nrows3;
      const float* wbase = isB2 ? S.fc2 : S.fc3;
      const float* bb    = isB2 ? S.fc2b : S.fc3b;
      for (int r = 0; r < 13; ++r) {
        if (r >= nr) break;
        float acc = 0.f;
        const float* wrow = wbase + r*512;
        #pragma unroll
        for (int tt = 0; tt < 8; ++tt) {
          float4 w4 = *(const float4*)&wrow[j16*4 + tt*64];
          acc += dot4(xr2[tt], w4);
        }
        acc = red16_add(acc);
        if (j16 == 0) {
          if (isB2) {
            float hvv = acc + bb[r];
            h2g[pT*(K*512) + s22*512 + base2 + r] = (hvv >= 0.f) ? hvv : 0.01f*hvv;
          } else {
            logg[pT1*(K*260) + s22*260 + base3 + r] = acc + bb[r];
          }
        }
      }
    }
    __syncthreads();   // sync1 (attn + spec ready)

    // ---- P2: wave0 verify+commit D | waves1-3 slice-gather+agg ----
    if (wave == 0) {
      if (nD > 0) {
        int nused = S.scali[0];
        const int nspec = nused;
        float lpp = S.scalf[0];
        #pragma unroll 1
        for (int s2 = 0; s2 < nD; ++s2) {
          const int vD = v0D + s2;
          float bp; int bi;
          if (nused == nspec) { bp = S.bpv[s2]; bi = S.biv[s2]; }
          else {
            d_scan(S.colors, S.nbrs[iD][s2], S.logits + s2*260, nused, lane, bp, bi);
          }
          const int isnew  = (bi == NPCC) ? 1 : 0;
          const int chosen = isnew ? nused : bi;
          nused += isnew;
          lpp += logf(bp + 1e-8f) - logf(1e-8f);
          if (lane == 0) {
            S.colors[vD] = (unsigned char)(chosen + 1);
            S.chosen[s2] = chosen;
          }
          if (b == 0) {
            float pp = (lane < 32) ? ppre[s2] : 0.f;
            #pragma unroll
            for (int off = 1; off < 32; off <<= 1) pp += __shfl_xor(pp, off, 64);
            if (lane == 0) eHvg[vD] = pp + S.ohdot[chosen];
          }
        }
        if (lane == 0) { S.scali[0] = nused; S.scalf[0] = lpp; }
      }
    } else {
      const int s = (t - 64) >> 4;
      const int c = t & 15;
      if (s < n) {
        const int vv = va + s;
        float gv[16];
        #pragma unroll
        for (int j = 0; j < 16; ++j) {
          int u = S.nbrs[tk][s][j];
          gv[j] = (u < vv) ? HF[(size_t)u*EMBD + kbase + c] : 0.f;
        }
        float acc = 0.f;
        #pragma unroll
        for (int j = 0; j < 16; ++j) acc += S.attn[s][j+1] * gv[j];
        float nv = (acc > 0.f) ? acc : expm1f(acc);
        nweg[pT*(K*512) + s*512 + kbase + c] = nv;
      }
    }
    __syncthreads();   // sync2 (chosen ready)

    // ---- P3: W_oh fold (batch iD) + A2 batched fc1+He (batch iA2) ----
    {
      const bool foldAct = (t < nD*16);
      const int fsp = t >> 4, fj = t & 15;
      float foldOld = 0.f, foldW = 0.f;
      if (foldAct) {
        foldOld = HF[(size_t)(v0D+fsp)*EMBD + kbase + fj];
        foldW   = W[(size_t)(512 + S.chosen[fsp])*512 + kbase + fj];
      }
      const int r = wave*4 + g;
      float acc1[K], acc2[K];
      #pragma unroll
      for (int s = 0; s < K; ++s) { acc1[s] = 0.f; acc2[s] = 0.f; }
      const float* w1row = S.fc1 + r*512;
      const float* w2row = S.wembT + r*512;
      #pragma unroll
      for (int tt = 0; tt < 8; ++tt) {
        float4 w1 = *(const float4*)&w1row[j16*4 + tt*64];
        float4 w2 = *(const float4*)&w2row[j16*4 + tt*64];
        #pragma unroll
        for (int s = 0; s < K; ++s) {
          if (s < nA2) {
            float4 x4 = *(const float4*)&S.newe8[s][j16*4 + tt*64];
            acc1[s] += dot4(x4, w1);
            acc2[s] += dot4(x4, w2);
          }
        }
      }
      if (foldAct) HF[(size_t)(v0D+fsp)*EMBD + kbase + fj] = foldOld + foldW;
      #pragma unroll
      for (int s = 0; s < K; ++s) {
        if (s < nA2) {
          float a1r = red16_add(acc1[s]);
          float a2r = red16_add(acc2[s]);
          if (j16 == 0) {
            float hvv = a1r + S.fc1b[r];
            h1g[pT1*(K*512) + s*512 + kbase + r] = (hvv >= 0.f) ? hvv : 0.01f*hvv;
            HF[(size_t)(v0A2+s)*EMBD + kbase + r] = a2r;
            S.hev[s][r] = a2r;
          }
        }
      }
    }
    __syncthreads();   // sync3

    // ---- eH partial publish (batch iA2) + global barrier ----
    if (t < nA2) {
      float pp = 0.f;
      #pragma unroll
      for (int kk = 0; kk < 16; ++kk) pp += S.hev[t][kk] * S.a2[kbase + kk];
      eHpg[((v0A2+t)&63)*32 + b] = pp;
    }
    __syncthreads();
    ++ep;
    if (t == 0) __hip_atomic_store(&flags[b*32], ep, __ATOMIC_RELEASE, __HIP_MEMORY_SCOPE_AGENT);
    if (t < 32) {
      while (__hip_atomic_load(&flags[t*32], __ATOMIC_RELAXED, __HIP_MEMORY_SCOPE_AGENT) < ep) { }
    }
    if (t == 0) (void)__hip_atomic_load(&flags[0], __ATOMIC_ACQUIRE, __HIP_MEMORY_SCOPE_AGENT);
    __syncthreads();

    // ---- advance ----
    if (nD > 0) d_done = v0D + nD - 1;
    va += n;
    ++T;
    if (d_done == NV-1) break;
    if (T > 12000u) break;   // safety: fail validation instead of hanging
  }

  // ================= output =================
  if (b == 0) {
    for (int i = t; i < NV; i += TPB) out[i] = (float)((int)S.colors[i] - 1);
    if (t == 0) {
      int bv = basep[0];
      int bl = (bv >= -100000 && bv <= 100000) ? bv : (int)__int_as_float(bv);
      float loss = ((float)(S.scali[0] - bl)) * S.scalf[0] / 8192.0f + 0.05f * S.scalf[1];
      out[NV] = loss;
    }
  }
}

extern "C" void kernel_launch(void* const* d_in, const int* in_sizes, int n_in,
                              void* d_out, int out_size, void* d_ws, size_t ws_size,
                              hipStream_t stream) {
  const int*   adj  = (const int*)d_in[0];
  const float* W    = (const float*)d_in[1];
  const float* av   = (const float*)d_in[2];
  const float* f1w  = (const float*)d_in[3];
  const float* f1b  = (const float*)d_in[4];
  const float* f2w  = (const float*)d_in[5];
  const float* f2b  = (const float*)d_in[6];
  const float* f3w  = (const float*)d_in[7];
  const float* f3b  = (const float*)d_in[8];
  const int*   bas  = (const int*)d_in[9];
  float* out = (float*)d_out;
  unsigned char* ws = (unsigned char*)d_ws;

  // zero barrier flags (workspace is poisoned 0xAA before every launch)
  (void)hipMemsetAsync(d_ws, 0, 8192, stream);
  (void)hipFuncSetAttribute((const void*)gc_kernel,
                      hipFuncAttributeMaxDynamicSharedMemorySize,
                      (int)sizeof(Smem));
  gc_kernel<<<dim3(GBLK), dim3(TPB), sizeof(Smem), stream>>>(
      adj, W, av, f1w, f1b, f2w, f2b, f3w, f3b, bas, out, ws);
}

// Round 9
// 24992.218 us; speedup vs baseline: 2.0819x; 1.2738x over previous
//
#include <hip/hip_runtime.h>
#include <math.h>

#define NV    8192
#define DEG   16
#define EMBD  512
#define NPCC  256
#define NL    257
#define GBLK  32
#define TPB   512
#define K     12

// workspace layout (bytes)
#define WS_FLAG  0        // 32 flags, 128B apart (4 KB)
#define WS_SSQ   4096
#define WS_OHD   5120
#define WS_H1    8192     // ring2 x K x 512 f (49152)
#define WS_H2    57344    // ring2 x K x 512 f (49152)
#define WS_LOG   106496   // ring2 x K x 260 f (24960)
#define WS_NWE   131456   // ring2 x K x 512 f (49152)
#define WS_EHP   180608   // ring64 x 32 f (8192)
#define WS_EHV   188800   // 8192 f (32768)
#define WS_HF    221568   // 8192*512 f = 16 MB

struct __align__(16) Smem {
  float wembT[16*512];   // W[:, kslice] transposed: [out][in]
  float fc1[16*512];
  float fc2[13*512];     // padded rows zero
  float fc3[9*512];      // padded rows/cols zero
  float ohdot[256];
  float a2[512];
  float newe8[K][512];   // full newe of batch T-1 (staged from nweg)
  float e[K][20];
  float attn[K][20];
  float hev[K][16];
  float bpv[K];
  int   biv[K];
  float fc1b[16];
  float fc2b[16];
  float fc3b[16];
  float red[32];
  float scalf[4];        // 0: lpp, 1: reg
  int   scali[4];        // 0: n_used
  int   nbrs[8][K][16];  // ring by tick&7
  int   bmeta[8][2];     // ring: v0, n
  int   chosen[K];
  int   slotbad[K];
  unsigned char colors[NV];
};
static_assert(sizeof(Smem) <= 160*1024, "LDS overflow");

__device__ __forceinline__ float dot4(const float4 a, const float4 b) {
  return a.x*b.x + a.y*b.y + a.z*b.z + a.w*b.w;
}
__device__ __forceinline__ float red64_add(float x) {
  #pragma unroll
  for (int off = 1; off < 64; off <<= 1) x += __shfl_xor(x, off, 64);
  return x;
}
__device__ __forceinline__ float red16_add(float x) {
  #pragma unroll
  for (int off = 1; off < 16; off <<= 1) x += __shfl_xor(x, off, 64);
  return x;
}

// masked softmax-argmax scan over 257 candidates; arithmetic identical to R8.
__device__ __forceinline__ void d_scan(const unsigned char* colors, const int* nbrsD,
                                       const float* lg, int nused, int lane,
                                       float& bp_out, int& bi_out) {
  int nc[DEG];
  #pragma unroll
  for (int j = 0; j < DEG; ++j) nc[j] = (int)colors[nbrsD[j]] - 1;
  float sv[5]; float bmx = -INFINITY;
  #pragma unroll
  for (int p = 0; p < 5; ++p) {
    int idx = lane + p*64;
    float val = -INFINITY;
    if (idx < NL) {
      val = lg[idx];
      bool msk = (idx >= nused) && (idx < NPCC);
      #pragma unroll
      for (int j = 0; j < DEG; ++j) msk |= (idx == nc[j]);
      if (msk) val = -INFINITY;
    }
    sv[p] = val;
    bmx = fmaxf(bmx, val);
  }
  #pragma unroll
  for (int off = 1; off < 64; off <<= 1) bmx = fmaxf(bmx, __shfl_xor(bmx, off, 64));
  float ssum = 0.f;
  #pragma unroll
  for (int p = 0; p < 5; ++p) ssum += expf(sv[p] - bmx);
  #pragma unroll
  for (int off = 1; off < 64; off <<= 1) ssum += __shfl_xor(ssum, off, 64);
  float bp = -1.f; int bi = NL + 10;
  #pragma unroll
  for (int p = 0; p < 5; ++p) {
    int idx = lane + p*64;
    float pj = (idx < NL) ? (expf(sv[p] - bmx) / ssum) : -1.f;
    if (pj > bp) { bp = pj; bi = idx; }
  }
  #pragma unroll
  for (int off = 1; off < 64; off <<= 1) {
    float op = __shfl_xor(bp, off, 64);
    int   oi = __shfl_xor(bi, off, 64);
    if (op > bp || (op == bp && oi < bi)) { bp = op; bi = oi; }
  }
  bp_out = bp; bi_out = bi;
}

__global__ void __launch_bounds__(TPB, 1)
gc_kernel(const int* __restrict__ adj, const float* __restrict__ W,
          const float* __restrict__ a, const float* __restrict__ fc1w,
          const float* __restrict__ fc1b_g, const float* __restrict__ fc2w,
          const float* __restrict__ fc2b_g, const float* __restrict__ fc3w,
          const float* __restrict__ fc3b_g, const int* __restrict__ basep,
          float* __restrict__ out, unsigned char* __restrict__ ws)
{
  extern __shared__ char smem_raw[];
  Smem& S = *reinterpret_cast<Smem*>(smem_raw);
  const int b    = blockIdx.x;
  const int t    = threadIdx.x;
  const int wave = t >> 6;
  const int lane = t & 63;
  const int g    = lane >> 4;
  const int j16  = lane & 15;

  unsigned* flags = (unsigned*)(ws + WS_FLAG);
  float* ssqP  = (float*)(ws + WS_SSQ);
  float* ohdg  = (float*)(ws + WS_OHD);
  float* h1g   = (float*)(ws + WS_H1);
  float* h2g   = (float*)(ws + WS_H2);
  float* logg  = (float*)(ws + WS_LOG);
  float* nweg  = (float*)(ws + WS_NWE);
  float* eHpg  = (float*)(ws + WS_EHP);
  float* eHvg  = (float*)(ws + WS_EHV);
  float* HF    = (float*)(ws + WS_HF);

  const int kbase  = b * 16;
  const int nrows2 = (b < 16) ? 13 : 12;
  const int base2  = (b < 16) ? 13*b : 208 + 12*(b-16);
  const int nrows3 = (b == 0) ? 9 : 8;
  const int base3  = (b == 0) ? 0 : 8*b + 1;

  // ================= init =================
  for (int i = t; i < EMBD; i += TPB) S.a2[i] = a[EMBD + i];
  for (int i = t; i < 16*512; i += TPB) S.fc1[i] = fc1w[(size_t)kbase*512 + i];
  for (int i = t; i < 13*512; i += TPB) {
    int rr = i >> 9;
    S.fc2[i] = (rr < nrows2) ? fc2w[(size_t)base2*512 + i] : 0.f;
  }
  for (int i = t; i < 9*512; i += TPB) {
    int rr = i >> 9, cc = i & 511;
    S.fc3[i] = (rr < nrows3 && cc < 400) ? fc3w[(size_t)(base3+rr)*400 + cc] : 0.f;
  }
  for (int i = t; i < 512; i += TPB) {
    const float* src = W + (size_t)i*512 + kbase;
    #pragma unroll
    for (int kk = 0; kk < 16; ++kk) S.wembT[kk*512 + i] = src[kk];
  }
  if (t < 16) {
    S.fc1b[t] = fc1b_g[kbase + t];
    S.fc2b[t] = (t < nrows2) ? fc2b_g[base2 + t] : 0.f;
    S.fc3b[t] = (t < nrows3) ? fc3b_g[base3 + t] : 0.f;
  }
  for (int i = t; i < NV/4; i += TPB) ((int*)S.colors)[i] = 0;
  if (t < 16) ((int*)S.bmeta)[t] = 0;
  if (t == 0) {
    S.colors[0] = 1;     // vertex 0: color 0
    S.scali[0] = 1;      // n_used
    S.scalf[0] = 0.f;    // lpp
  }
  // ohdot slice (8 values per block, one per wave); block 0 publishes eHval[0]
  {
    int c = b*8 + wave;
    const float* wr = W + (size_t)(512 + c)*512;
    float acc = 0.f;
    #pragma unroll
    for (int p = 0; p < 2; ++p) {
      float4 w4 = *(const float4*)&wr[p*256 + lane*4];
      float4 a4 = *(const float4*)&a[EMBD + p*256 + lane*4];
      acc += dot4(w4, a4);
    }
    acc = red64_add(acc);
    if (lane == 0) {
      ohdg[c] = acc;
      if (c == 0) eHvg[0] = acc;   // eH(0) = dot(W_oh[0], a2)
    }
  }
  __syncthreads();
  // HF row 0 = W_oh[0] (this block's slice) straight from global W
  if (t < 16) HF[kbase + t] = W[(size_t)512*512 + kbase + t];
  // sum-of-squares partials for reg
  {
    float s0=0.f, s1=0.f, s2=0.f, s3=0.f;
    for (int i = t; i < 16*512; i += TPB) {
      float x = S.wembT[i]; s0 += x*x;
      x = S.fc1[i]; s1 += x*x;
    }
    for (int i = t; i < 13*512; i += TPB) { float x = S.fc2[i]; s2 += x*x; }
    for (int i = t; i < 9*512; i += TPB)  { float x = S.fc3[i]; s3 += x*x; }
    for (int i = t; i < 4096; i += TPB) {   // W_oh slice from global
      int c = i >> 4, kk = i & 15;
      float x = W[(size_t)(512 + c)*512 + kbase + kk];
      s0 += x*x;
    }
    s0 = red64_add(s0); s1 = red64_add(s1); s2 = red64_add(s2); s3 = red64_add(s3);
    if (lane == 0) { S.red[wave*4+0]=s0; S.red[wave*4+1]=s1; S.red[wave*4+2]=s2; S.red[wave*4+3]=s3; }
    __syncthreads();
    if (t == 0) {
      for (int m = 0; m < 4; ++m) {
        float s = 0.f;
        for (int w = 0; w < 8; ++w) s += S.red[w*4 + m];
        ssqP[m*GBLK + b] = s;
      }
    }
  }
  // ---- init barrier ----
  unsigned ep = 1;
  __syncthreads();
  if (t == 0) __hip_atomic_store(&flags[b*32], ep, __ATOMIC_RELEASE, __HIP_MEMORY_SCOPE_AGENT);
  if (t < 32) {
    while (__hip_atomic_load(&flags[t*32], __ATOMIC_RELAXED, __HIP_MEMORY_SCOPE_AGENT) < ep) { }
  }
  if (t == 0) (void)__hip_atomic_load(&flags[0], __ATOMIC_ACQUIRE, __HIP_MEMORY_SCOPE_AGENT);
  __syncthreads();

  if (t < 256) S.ohdot[t] = ohdg[t];
  if (b == 0 && t == 0) {
    float reg = 0.f;
    for (int m = 0; m < 4; ++m) {
      float s = 0.f;
      for (int bb = 0; bb < GBLK; ++bb) s += ssqP[m*GBLK + bb];
      reg += sqrtf(s);
    }
    S.scalf[1] = reg;
  }
  __syncthreads();

  // ================= 5-stage pipelined main loop =================
  // tick T: A1(batch T) stage+gather-slice | A2(T-1) fc1+He | B(T-2) fc2
  //         | C(T-3) fc3 | D(T-4) argmax+commit+fold
  int va = 1, d_done = 0;
  unsigned T = 0;

  #pragma unroll 1
  for (;;) {
    const int tk   = (int)(T & 7);
    const int iA2  = (int)((T+7) & 7);
    const int iB   = (int)((T+6) & 7);
    const int iC   = (int)((T+5) & 7);
    const int iD   = (int)((T+4) & 7);
    const int v0A2 = S.bmeta[iA2][0], nA2 = S.bmeta[iA2][1];
    const int nB   = S.bmeta[iB][1];
    const int nC   = S.bmeta[iC][1];
    const int v0D  = S.bmeta[iD][0],  nD  = S.bmeta[iD][1];
    const bool canA = (va < NV);
    const int Kc = canA ? ((NV - va < K) ? (NV - va) : K) : 0;
    const int pT  = (int)(T & 1);
    const int pT1 = pT ^ 1;
    const float* lgD = logg + pT*(K*260);

    // ---- P0: stage batch + newe-full + BC xr prefetch ----
    if (t < Kc*DEG) {
      int s = t >> 4, j = t & 15;
      int v = va + s;
      int u = adj[v*DEG + j];
      S.nbrs[tk][s][j] = u;
      bool bad = false;
      float er = 0.f;
      if (u < v) {
        if (u > d_done) bad = true;
        else { float eh = eHvg[u]; er = (eh >= 0.f) ? eh : 0.2f*eh; }
      }
      S.e[s][j+1] = er;
      unsigned long long bm = __ballot(bad);
      if (j == 0) S.slotbad[s] = (int)((bm >> (((t >> 4) & 3)*16)) & 0xFFFFull);
    }
    if (t < K) S.e[t][0] = 0.f;
    for (int x = t; x < nA2*128; x += TPB)
      ((float4*)S.newe8)[x] = ((const float4*)(nweg + pT1*(K*512)))[x];
    // BC xr prefetch (32 groups cover tot<=24 in ONE pass)
    const int grp = t >> 4;
    const int tot = nB + nC;
    float4 xr[8];
    const bool hasJob = (grp < tot);
    const bool isB = hasJob && (grp < nB);
    const int s2j = isB ? grp : grp - nB;
    if (hasJob) {
      const float* xp = isB ? (h1g + pT*(K*512) + s2j*512)
                            : (h2g + pT1*(K*512) + s2j*512);
      #pragma unroll
      for (int tt = 0; tt < 8; ++tt) xr[tt] = *(const float4*)&xp[j16*4 + tt*64];
    }
    __syncthreads();   // sync0

    int n = 0;
    while (n < Kc && S.slotbad[n] == 0) ++n;
    if (t == 0) { S.bmeta[tk][0] = va; S.bmeta[tk][1] = n; }

    // ---- P1: softmax (w2) + D-spec + BC + A2 fc1/He ----
    if (wave == 2 && lane < n) {
      float m = 0.f;   // includes e[0]=0
      #pragma unroll
      for (int j = 1; j <= DEG; ++j) m = fmaxf(m, S.e[lane][j]);
      float ex[DEG+1]; float ssum = 0.f;
      #pragma unroll
      for (int j = 0; j <= DEG; ++j) { ex[j] = expf(S.e[lane][j] - m); ssum += ex[j]; }
      #pragma unroll
      for (int j = 0; j <= DEG; ++j) S.attn[lane][j] = ex[j] / ssum;
    }
    // ppre prefetch for eH finalize (wave0, block 0)
    float ppre[K];
    #pragma unroll
    for (int s2 = 0; s2 < K; ++s2) ppre[s2] = 0.f;
    if (b == 0 && wave == 0 && lane < 32) {
      #pragma unroll
      for (int s2 = 0; s2 < K; ++s2)
        if (s2 < nD) ppre[s2] = eHpg[((v0D+s2)&63)*32 + lane];
    }
    // D-speculative scans: wave w -> slots {w, w+8}
    {
      const int nspec = S.scali[0];
      #pragma unroll
      for (int rep = 0; rep < 2; ++rep) {
        int s2 = wave + rep*8;
        if (s2 < nD) {
          float bp; int bi;
          d_scan(S.colors, S.nbrs[iD][s2], lgD + s2*260, nspec, lane, bp, bi);
          if (lane == 0) { S.bpv[s2] = bp; S.biv[s2] = bi; }
        }
      }
    }
    // BC compute (single pass)
    if (hasJob) {
      const int nr = isB ? nrows2 : nrows3;
      const float* wbase = isB ? S.fc2 : S.fc3;
      const float* bb    = isB ? S.fc2b : S.fc3b;
      for (int r = 0; r < 13; ++r) {
        if (r >= nr) break;
        float acc = 0.f;
        const float* wrow = wbase + r*512;
        #pragma unroll
        for (int tt = 0; tt < 8; ++tt) {
          float4 w4 = *(const float4*)&wrow[j16*4 + tt*64];
          acc += dot4(xr[tt], w4);
        }
        acc = red16_add(acc);
        if (j16 == 0) {
          if (isB) {
            float hvv = acc + bb[r];
            h2g[pT*(K*512) + s2j*512 + base2 + r] = (hvv >= 0.f) ? hvv : 0.01f*hvv;
          } else {
            logg[pT1*(K*260) + s2j*260 + base3 + r] = acc + bb[r];
          }
        }
      }
    }
    // A2: waves 0-3 fc1 rows, waves 4-7 He rows (batch iA2)
    {
      const int r = (wave & 3)*4 + g;
      const bool doFc1 = (wave < 4);
      const float* wrow = doFc1 ? (S.fc1 + r*512) : (S.wembT + r*512);
      float acc[K];
      #pragma unroll
      for (int s = 0; s < K; ++s) acc[s] = 0.f;
      #pragma unroll
      for (int tt = 0; tt < 8; ++tt) {
        float4 w4 = *(const float4*)&wrow[j16*4 + tt*64];
        #pragma unroll
        for (int s = 0; s < K; ++s) {
          if (s < nA2) {
            float4 x4 = *(const float4*)&S.newe8[s][j16*4 + tt*64];
            acc[s] += dot4(x4, w4);
          }
        }
      }
      #pragma unroll
      for (int s = 0; s < K; ++s) {
        if (s < nA2) {
          float ar = red16_add(acc[s]);
          if (j16 == 0) {
            if (doFc1) {
              float hvv = ar + S.fc1b[r];
              h1g[pT1*(K*512) + s*512 + kbase + r] = (hvv >= 0.f) ? hvv : 0.01f*hvv;
            } else {
              HF[(size_t)(v0A2+s)*EMBD + kbase + r] = ar;
              S.hev[s][r] = ar;
            }
          }
        }
      }
    }
    __syncthreads();   // sync1

    // ---- P2: wave0 verify+commit D | waves1-7 slice-gather+agg ----
    if (wave == 0) {
      if (nD > 0) {
        int nused = S.scali[0];
        const int nspec = nused;
        float lpp = S.scalf[0];
        #pragma unroll 1
        for (int s2 = 0; s2 < nD; ++s2) {
          const int vD = v0D + s2;
          float bp; int bi;
          if (nused == nspec) { bp = S.bpv[s2]; bi = S.biv[s2]; }
          else {
            d_scan(S.colors, S.nbrs[iD][s2], lgD + s2*260, nused, lane, bp, bi);
          }
          const int isnew  = (bi == NPCC) ? 1 : 0;
          const int chosen = isnew ? nused : bi;
          nused += isnew;
          lpp += logf(bp + 1e-8f) - logf(1e-8f);
          if (lane == 0) {
            S.colors[vD] = (unsigned char)(chosen + 1);
            S.chosen[s2] = chosen;
          }
          if (b == 0) {
            float pp = (lane < 32) ? ppre[s2] : 0.f;
            #pragma unroll
            for (int off = 1; off < 32; off <<= 1) pp += __shfl_xor(pp, off, 64);
            if (lane == 0) eHvg[vD] = pp + S.ohdot[chosen];
          }
        }
        if (lane == 0) { S.scali[0] = nused; S.scalf[0] = lpp; }
      }
    } else {
      const int s = (t - 64) >> 4;
      const int c = t & 15;
      if (s < n) {
        const int vv = va + s;
        float gv[16];
        #pragma unroll
        for (int j = 0; j < 16; ++j) {
          int u = S.nbrs[tk][s][j];
          gv[j] = (u < vv) ? HF[(size_t)u*EMBD + kbase + c] : 0.f;
        }
        float acc = 0.f;
        #pragma unroll
        for (int j = 0; j < 16; ++j) acc += S.attn[s][j+1] * gv[j];
        float nv = (acc > 0.f) ? acc : expm1f(acc);
        nweg[pT*(K*512) + s*512 + kbase + c] = nv;
      }
    }
    __syncthreads();   // sync2 (chosen ready)

    // ---- P3: W_oh fold (batch iD) + eH partial publish (batch iA2) ----
    if (t < nD*16) {
      const int fsp = t >> 4, fj = t & 15;
      HF[(size_t)(v0D+fsp)*EMBD + kbase + fj] +=
          W[(size_t)(512 + S.chosen[fsp])*512 + kbase + fj];
    }
    if (t < nA2) {
      float pp = 0.f;
      #pragma unroll
      for (int kk = 0; kk < 16; ++kk) pp += S.hev[t][kk] * S.a2[kbase + kk];
      eHpg[((v0A2+t)&63)*32 + b] = pp;
    }
    __syncthreads();   // sync3
    ++ep;
    if (t == 0) __hip_atomic_store(&flags[b*32], ep, __ATOMIC_RELEASE, __HIP_MEMORY_SCOPE_AGENT);
    if (t < 32) {
      while (__hip_atomic_load(&flags[t*32], __ATOMIC_RELAXED, __HIP_MEMORY_SCOPE_AGENT) < ep) { }
    }
    if (t == 0) (void)__hip_atomic_load(&flags[0], __ATOMIC_ACQUIRE, __HIP_MEMORY_SCOPE_AGENT);
    __syncthreads();

    // ---- advance ----
    if (nD > 0) d_done = v0D + nD - 1;
    va += n;
    ++T;
    if (d_done == NV-1) break;
    if (T > 12000u) break;   // safety: fail validation instead of hanging
  }

  // ================= output =================
  if (b == 0) {
    for (int i = t; i < NV; i += TPB) out[i] = (float)((int)S.colors[i] - 1);
    if (t == 0) {
      int bv = basep[0];
      int bl = (bv >= -100000 && bv <= 100000) ? bv : (int)__int_as_float(bv);
      float loss = ((float)(S.scali[0] - bl)) * S.scalf[0] / 8192.0f + 0.05f * S.scalf[1];
      out[NV] = loss;
    }
  }
}

extern "C" void kernel_launch(void* const* d_in, const int* in_sizes, int n_in,
                              void* d_out, int out_size, void* d_ws, size_t ws_size,
                              hipStream_t stream) {
  const int*   adj  = (const int*)d_in[0];
  const float* W    = (const float*)d_in[1];
  const float* av   = (const float*)d_in[2];
  const float* f1w  = (const float*)d_in[3];
  const float* f1b  = (const float*)d_in[4];
  const float* f2w  = (const float*)d_in[5];
  const float* f2b  = (const float*)d_in[6];
  const float* f3w  = (const float*)d_in[7];
  const float* f3b  = (const float*)d_in[8];
  const int*   bas  = (const int*)d_in[9];
  float* out = (float*)d_out;
  unsigned char* ws = (unsigned char*)d_ws;

  // zero barrier flags (workspace is poisoned 0xAA before every launch)
  (void)hipMemsetAsync(d_ws, 0, 8192, stream);
  (void)hipFuncSetAttribute((const void*)gc_kernel,
                      hipFuncAttributeMaxDynamicSharedMemorySize,
                      (int)sizeof(Smem));
  gc_kernel<<<dim3(GBLK), dim3(TPB), sizeof(Smem), stream>>>(
      adj, W, av, f1w, f1b, f2w, f2b, f3w, f3b, bas, out, ws);
}

// Round 10
// 24609.518 us; speedup vs baseline: 2.1142x; 1.0156x over previous
//
#include <hip/hip_runtime.h>
#include <math.h>

#define NV    8192
#define DEG   16
#define EMBD  512
#define NPCC  256
#define NL    257
#define GBLK  32
#define TPB   512
#define K     14

// workspace layout (bytes)
#define WS_FLAG  0        // 32 flags, 128B apart (4 KB)
#define WS_SSQ   4096
#define WS_OHD   5120
#define WS_H1    8192     // ring2 x K x 512 f (57344)
#define WS_H2    65536    // ring2 x K x 512 f (57344)
#define WS_LOG   122880   // ring2 x K x 260 f (29120)
#define WS_NWE   152064   // ring2 x K x 512 f (57344)
#define WS_EHP   209408   // ring64 x 32 f (8192)
#define WS_EHV   217600   // 8192 f (32768)
#define WS_HF    262144   // 8192*512 f = 16 MB

struct __align__(16) Smem {
  float wembT[16*512];   // W[:, kslice] transposed: [out][in]
  float fc1[16*512];
  float fc2[13*512];     // padded rows zero
  float fc3[9*512];      // padded rows/cols zero
  float ohdot[256];
  float a2[512];
  float newe8[K][512];   // full newe of batch T-1 (staged from nweg)
  float e[K][20];
  float attn[K][20];
  float hev[K][16];
  float bpv[K];
  int   biv[K];
  float fc1b[16];
  float fc2b[16];
  float fc3b[16];
  float red[32];
  float scalf[4];        // 0: lpp, 1: reg
  int   scali[4];        // 0: n_used
  int   nbrs[8][K][16];  // ring by tick&7
  int   bmeta[8][2];     // ring: v0, n
  int   chosen[K];       // batch committed LAST tick (folded this tick P0)
  int   slotbad[K];
  unsigned char colors[NV];
};
static_assert(sizeof(Smem) <= 160*1024, "LDS overflow");

__device__ __forceinline__ float dot4(const float4 a, const float4 b) {
  return a.x*b.x + a.y*b.y + a.z*b.z + a.w*b.w;
}
__device__ __forceinline__ float red64_add(float x) {
  #pragma unroll
  for (int off = 1; off < 64; off <<= 1) x += __shfl_xor(x, off, 64);
  return x;
}
__device__ __forceinline__ float red16_add(float x) {
  #pragma unroll
  for (int off = 1; off < 16; off <<= 1) x += __shfl_xor(x, off, 64);
  return x;
}

// masked softmax-argmax over 257 candidates, logits pre-loaded (idx>=NL => -INF).
// Arithmetic identical to R9's d_scan.
__device__ __forceinline__ void d_scan_pre(const unsigned char* colors, const int* nbrsD,
                                           const float svin[5], int nused, int lane,
                                           float& bp_out, int& bi_out) {
  int nc[DEG];
  #pragma unroll
  for (int j = 0; j < DEG; ++j) nc[j] = (int)colors[nbrsD[j]] - 1;
  float sv[5]; float bmx = -INFINITY;
  #pragma unroll
  for (int p = 0; p < 5; ++p) {
    int idx = lane + p*64;
    float val = svin[p];
    bool msk = (idx >= nused) && (idx < NPCC);
    #pragma unroll
    for (int j = 0; j < DEG; ++j) msk |= (idx == nc[j]);
    if (msk || idx >= NL) val = -INFINITY;
    sv[p] = val;
    bmx = fmaxf(bmx, val);
  }
  #pragma unroll
  for (int off = 1; off < 64; off <<= 1) bmx = fmaxf(bmx, __shfl_xor(bmx, off, 64));
  float ssum = 0.f;
  #pragma unroll
  for (int p = 0; p < 5; ++p) ssum += expf(sv[p] - bmx);
  #pragma unroll
  for (int off = 1; off < 64; off <<= 1) ssum += __shfl_xor(ssum, off, 64);
  float bp = -1.f; int bi = NL + 10;
  #pragma unroll
  for (int p = 0; p < 5; ++p) {
    int idx = lane + p*64;
    float pj = (idx < NL) ? (expf(sv[p] - bmx) / ssum) : -1.f;
    if (pj > bp) { bp = pj; bi = idx; }
  }
  #pragma unroll
  for (int off = 1; off < 64; off <<= 1) {
    float op = __shfl_xor(bp, off, 64);
    int   oi = __shfl_xor(bi, off, 64);
    if (op > bp || (op == bp && oi < bi)) { bp = op; bi = oi; }
  }
  bp_out = bp; bi_out = bi;
}

__global__ void __launch_bounds__(TPB, 1)
gc_kernel(const int* __restrict__ adj, const float* __restrict__ W,
          const float* __restrict__ a, const float* __restrict__ fc1w,
          const float* __restrict__ fc1b_g, const float* __restrict__ fc2w,
          const float* __restrict__ fc2b_g, const float* __restrict__ fc3w,
          const float* __restrict__ fc3b_g, const int* __restrict__ basep,
          float* __restrict__ out, unsigned char* __restrict__ ws)
{
  extern __shared__ char smem_raw[];
  Smem& S = *reinterpret_cast<Smem*>(smem_raw);
  const int b    = blockIdx.x;
  const int t    = threadIdx.x;
  const int wave = t >> 6;
  const int lane = t & 63;
  const int g    = lane >> 4;
  const int j16  = lane & 15;

  unsigned* flags = (unsigned*)(ws + WS_FLAG);
  float* ssqP  = (float*)(ws + WS_SSQ);
  float* ohdg  = (float*)(ws + WS_OHD);
  float* h1g   = (float*)(ws + WS_H1);
  float* h2g   = (float*)(ws + WS_H2);
  float* logg  = (float*)(ws + WS_LOG);
  float* nweg  = (float*)(ws + WS_NWE);
  float* eHpg  = (float*)(ws + WS_EHP);
  float* eHvg  = (float*)(ws + WS_EHV);
  float* HF    = (float*)(ws + WS_HF);

  const int kbase  = b * 16;
  const int nrows2 = (b < 16) ? 13 : 12;
  const int base2  = (b < 16) ? 13*b : 208 + 12*(b-16);
  const int nrows3 = (b == 0) ? 9 : 8;
  const int base3  = (b == 0) ? 0 : 8*b + 1;

  // ================= init =================
  for (int i = t; i < EMBD; i += TPB) S.a2[i] = a[EMBD + i];
  for (int i = t; i < 16*512; i += TPB) S.fc1[i] = fc1w[(size_t)kbase*512 + i];
  for (int i = t; i < 13*512; i += TPB) {
    int rr = i >> 9;
    S.fc2[i] = (rr < nrows2) ? fc2w[(size_t)base2*512 + i] : 0.f;
  }
  for (int i = t; i < 9*512; i += TPB) {
    int rr = i >> 9, cc = i & 511;
    S.fc3[i] = (rr < nrows3 && cc < 400) ? fc3w[(size_t)(base3+rr)*400 + cc] : 0.f;
  }
  for (int i = t; i < 512; i += TPB) {
    const float* src = W + (size_t)i*512 + kbase;
    #pragma unroll
    for (int kk = 0; kk < 16; ++kk) S.wembT[kk*512 + i] = src[kk];
  }
  if (t < 16) {
    S.fc1b[t] = fc1b_g[kbase + t];
    S.fc2b[t] = (t < nrows2) ? fc2b_g[base2 + t] : 0.f;
    S.fc3b[t] = (t < nrows3) ? fc3b_g[base3 + t] : 0.f;
  }
  for (int i = t; i < NV/4; i += TPB) ((int*)S.colors)[i] = 0;
  if (t < 16) ((int*)S.bmeta)[t] = 0;
  if (t == 0) {
    S.colors[0] = 1;     // vertex 0: color 0
    S.scali[0] = 1;      // n_used
    S.scalf[0] = 0.f;    // lpp
  }
  // ohdot slice (8 values per block, one per wave); block 0 publishes eHval[0]
  {
    int c = b*8 + wave;
    const float* wr = W + (size_t)(512 + c)*512;
    float acc = 0.f;
    #pragma unroll
    for (int p = 0; p < 2; ++p) {
      float4 w4 = *(const float4*)&wr[p*256 + lane*4];
      float4 a4 = *(const float4*)&a[EMBD + p*256 + lane*4];
      acc += dot4(w4, a4);
    }
    acc = red64_add(acc);
    if (lane == 0) {
      ohdg[c] = acc;
      if (c == 0) eHvg[0] = acc;   // eH(0) = dot(W_oh[0], a2)
    }
  }
  __syncthreads();
  // HF row 0 = W_oh[0] (this block's slice) straight from global W
  if (t < 16) HF[kbase + t] = W[(size_t)512*512 + kbase + t];
  // sum-of-squares partials for reg
  {
    float s0=0.f, s1=0.f, s2=0.f, s3=0.f;
    for (int i = t; i < 16*512; i += TPB) {
      float x = S.wembT[i]; s0 += x*x;
      x = S.fc1[i]; s1 += x*x;
    }
    for (int i = t; i < 13*512; i += TPB) { float x = S.fc2[i]; s2 += x*x; }
    for (int i = t; i < 9*512; i += TPB)  { float x = S.fc3[i]; s3 += x*x; }
    for (int i = t; i < 4096; i += TPB) {   // W_oh slice from global
      int c = i >> 4, kk = i & 15;
      float x = W[(size_t)(512 + c)*512 + kbase + kk];
      s0 += x*x;
    }
    s0 = red64_add(s0); s1 = red64_add(s1); s2 = red64_add(s2); s3 = red64_add(s3);
    if (lane == 0) { S.red[wave*4+0]=s0; S.red[wave*4+1]=s1; S.red[wave*4+2]=s2; S.red[wave*4+3]=s3; }
    __syncthreads();
    if (t == 0) {
      for (int m = 0; m < 4; ++m) {
        float s = 0.f;
        for (int w = 0; w < 8; ++w) s += S.red[w*4 + m];
        ssqP[m*GBLK + b] = s;
      }
    }
  }
  // ---- init barrier ----
  unsigned ep = 1;
  __syncthreads();
  if (t == 0) __hip_atomic_store(&flags[b*32], ep, __ATOMIC_RELEASE, __HIP_MEMORY_SCOPE_AGENT);
  if (t < 32) {
    while (__hip_atomic_load(&flags[t*32], __ATOMIC_RELAXED, __HIP_MEMORY_SCOPE_AGENT) < ep) { }
  }
  if (t == 0) (void)__hip_atomic_load(&flags[0], __ATOMIC_ACQUIRE, __HIP_MEMORY_SCOPE_AGENT);
  __syncthreads();

  if (t < 256) S.ohdot[t] = ohdg[t];
  if (b == 0 && t == 0) {
    float reg = 0.f;
    for (int m = 0; m < 4; ++m) {
      float s = 0.f;
      for (int bb = 0; bb < GBLK; ++bb) s += ssqP[m*GBLK + bb];
      reg += sqrtf(s);
    }
    S.scalf[1] = reg;
  }
  __syncthreads();

  // ================= 5-stage pipelined main loop, 3 syncs + barrier =========
  // tick T: P0 stage(batch T) + fold(batch T-5, committed last tick)
  //         P1 A2 fc1/He(T-1) + B fc2(T-2) + C fc3(T-3) + D-spec(T-4)
  //         P2 wave0 commit D(T-4) | gather+agg(T) | eHpg publish(T-1)
  int va = 1, d_done = 0;
  unsigned T = 0;

  #pragma unroll 1
  for (;;) {
    const int tk   = (int)(T & 7);
    const int iA2  = (int)((T+7) & 7);
    const int iB   = (int)((T+6) & 7);
    const int iC   = (int)((T+5) & 7);
    const int iD   = (int)((T+4) & 7);
    const int iF   = (int)((T+3) & 7);
    const int v0A2 = S.bmeta[iA2][0], nA2 = S.bmeta[iA2][1];
    const int nB   = S.bmeta[iB][1];
    const int nC   = S.bmeta[iC][1];
    const int v0D  = S.bmeta[iD][0],  nD  = S.bmeta[iD][1];
    const int v0F  = S.bmeta[iF][0],  nF  = S.bmeta[iF][1];
    const bool canA = (va < NV);
    const int Kc = canA ? ((NV - va < K) ? (NV - va) : K) : 0;
    const int pT  = (int)(T & 1);
    const int pT1 = pT ^ 1;
    const float* lgD = logg + pT*(K*260);

    // ---- P0: fold(prev committed) + stage batch + newe staging + prefetch ----
    if (t < nF*16) {
      const int fsp = t >> 4, fj = t & 15;
      HF[(size_t)(v0F+fsp)*EMBD + kbase + fj] +=
          W[(size_t)(512 + S.chosen[fsp])*512 + kbase + fj];
    }
    if (t < Kc*DEG) {
      int s = t >> 4, j = t & 15;
      int v = va + s;
      int u = adj[v*DEG + j];
      S.nbrs[tk][s][j] = u;
      bool bad = false;
      float er = 0.f;
      if (u < v) {
        if (u > d_done) bad = true;
        else { float eh = eHvg[u]; er = (eh >= 0.f) ? eh : 0.2f*eh; }
      }
      S.e[s][j+1] = er;
      unsigned long long bm = __ballot(bad);
      if (j == 0) S.slotbad[s] = (int)((bm >> (((t >> 4) & 3)*16)) & 0xFFFFull);
    }
    if (t < K) S.e[t][0] = 0.f;
    for (int x = t; x < nA2*128; x += TPB)
      ((float4*)S.newe8)[x] = ((const float4*)(nweg + pT1*(K*512)))[x];
    // BC xr prefetch (32 groups cover tot<=28 in ONE pass)
    const int grp = t >> 4;
    const int tot = nB + nC;
    float4 xr[8];
    const bool hasJob = (grp < tot);
    const bool isB = hasJob && (grp < nB);
    const int s2j = isB ? grp : grp - nB;
    if (hasJob) {
      const float* xp = isB ? (h1g + pT*(K*512) + s2j*512)
                            : (h2g + pT1*(K*512) + s2j*512);
      #pragma unroll
      for (int tt = 0; tt < 8; ++tt) xr[tt] = *(const float4*)&xp[j16*4 + tt*64];
    }
    // spec logits prefetch: wave w -> slots {w, w+8}
    float svp[2][5];
    #pragma unroll
    for (int rep = 0; rep < 2; ++rep) {
      int s2 = wave + rep*8;
      #pragma unroll
      for (int p = 0; p < 5; ++p) {
        int idx = lane + p*64;
        svp[rep][p] = (s2 < nD && idx < NL) ? lgD[s2*260 + idx] : -INFINITY;
      }
    }
    // ppre prefetch for eH finalize (wave0, block 0)
    float ppre[K];
    #pragma unroll
    for (int s2 = 0; s2 < K; ++s2) ppre[s2] = 0.f;
    if (b == 0 && wave == 0 && lane < 32) {
      #pragma unroll
      for (int s2 = 0; s2 < K; ++s2)
        if (s2 < nD) ppre[s2] = eHpg[((v0D+s2)&63)*32 + lane];
    }
    __syncthreads();   // sync0

    int n = 0;
    while (n < Kc && S.slotbad[n] == 0) ++n;
    if (t == 0) { S.bmeta[tk][0] = va; S.bmeta[tk][1] = n; }

    // ---- P1: softmax (w2) + D-spec + BC + A2 fc1/He ----
    if (wave == 2 && lane < n) {
      float m = 0.f;   // includes e[0]=0
      #pragma unroll
      for (int j = 1; j <= DEG; ++j) m = fmaxf(m, S.e[lane][j]);
      float ex[DEG+1]; float ssum = 0.f;
      #pragma unroll
      for (int j = 0; j <= DEG; ++j) { ex[j] = expf(S.e[lane][j] - m); ssum += ex[j]; }
      #pragma unroll
      for (int j = 0; j <= DEG; ++j) S.attn[lane][j] = ex[j] / ssum;
    }
    // D-speculative scans (prefetched logits)
    {
      const int nspec = S.scali[0];
      #pragma unroll
      for (int rep = 0; rep < 2; ++rep) {
        int s2 = wave + rep*8;
        if (s2 < nD) {
          float bp; int bi;
          d_scan_pre(S.colors, S.nbrs[iD][s2], svp[rep], nspec, lane, bp, bi);
          if (lane == 0) { S.bpv[s2] = bp; S.biv[s2] = bi; }
        }
      }
    }
    // BC compute (single pass)
    if (hasJob) {
      const int nr = isB ? nrows2 : nrows3;
      const float* wbase = isB ? S.fc2 : S.fc3;
      const float* bb    = isB ? S.fc2b : S.fc3b;
      for (int r = 0; r < 13; ++r) {
        if (r >= nr) break;
        float acc = 0.f;
        const float* wrow = wbase + r*512;
        #pragma unroll
        for (int tt = 0; tt < 8; ++tt) {
          float4 w4 = *(const float4*)&wrow[j16*4 + tt*64];
          acc += dot4(xr[tt], w4);
        }
        acc = red16_add(acc);
        if (j16 == 0) {
          if (isB) {
            float hvv = acc + bb[r];
            h2g[pT*(K*512) + s2j*512 + base2 + r] = (hvv >= 0.f) ? hvv : 0.01f*hvv;
          } else {
            logg[pT1*(K*260) + s2j*260 + base3 + r] = acc + bb[r];
          }
        }
      }
    }
    // A2: waves 0-3 fc1 rows, waves 4-7 He rows (batch iA2)
    {
      const int r = (wave & 3)*4 + g;
      const bool doFc1 = (wave < 4);
      const float* wrow = doFc1 ? (S.fc1 + r*512) : (S.wembT + r*512);
      float acc[K];
      #pragma unroll
      for (int s = 0; s < K; ++s) acc[s] = 0.f;
      #pragma unroll
      for (int tt = 0; tt < 8; ++tt) {
        float4 w4 = *(const float4*)&wrow[j16*4 + tt*64];
        #pragma unroll
        for (int s = 0; s < K; ++s) {
          if (s < nA2) {
            float4 x4 = *(const float4*)&S.newe8[s][j16*4 + tt*64];
            acc[s] += dot4(x4, w4);
          }
        }
      }
      #pragma unroll
      for (int s = 0; s < K; ++s) {
        if (s < nA2) {
          float ar = red16_add(acc[s]);
          if (j16 == 0) {
            if (doFc1) {
              float hvv = ar + S.fc1b[r];
              h1g[pT1*(K*512) + s*512 + kbase + r] = (hvv >= 0.f) ? hvv : 0.01f*hvv;
            } else {
              HF[(size_t)(v0A2+s)*EMBD + kbase + r] = ar;
              S.hev[s][r] = ar;
            }
          }
        }
      }
    }
    __syncthreads();   // sync1

    // ---- P2: wave0 verify+commit D | gather+agg | eHpg publish ----
    if (wave == 0) {
      if (nD > 0) {
        int nused = S.scali[0];
        const int nspec = nused;
        float lpp = S.scalf[0];
        #pragma unroll 1
        for (int s2 = 0; s2 < nD; ++s2) {
          const int vD = v0D + s2;
          float bp; int bi;
          if (nused == nspec) { bp = S.bpv[s2]; bi = S.biv[s2]; }
          else {
            float sv[5];
            #pragma unroll
            for (int p = 0; p < 5; ++p) {
              int idx = lane + p*64;
              sv[p] = (idx < NL) ? lgD[s2*260 + idx] : -INFINITY;
            }
            d_scan_pre(S.colors, S.nbrs[iD][s2], sv, nused, lane, bp, bi);
          }
          const int isnew  = (bi == NPCC) ? 1 : 0;
          const int chosen = isnew ? nused : bi;
          nused += isnew;
          lpp += logf(bp + 1e-8f) - logf(1e-8f);
          if (lane == 0) {
            S.colors[vD] = (unsigned char)(chosen + 1);
            S.chosen[s2] = chosen;
          }
          if (b == 0) {
            float pp = (lane < 32) ? ppre[s2] : 0.f;
            #pragma unroll
            for (int off = 1; off < 32; off <<= 1) pp += __shfl_xor(pp, off, 64);
            if (lane == 0) eHvg[vD] = pp + S.ohdot[chosen];
          }
        }
        if (lane == 0) { S.scali[0] = nused; S.scalf[0] = lpp; }
      }
    } else {
      const int gi = (t - 64) >> 4;
      if (gi < n) {
        const int s = gi;
        const int c = t & 15;
        const int vv = va + s;
        float gv[16];
        #pragma unroll
        for (int j = 0; j < 16; ++j) {
          int u = S.nbrs[tk][s][j];
          gv[j] = (u < vv) ? HF[(size_t)u*EMBD + kbase + c] : 0.f;
        }
        float acc = 0.f;
        #pragma unroll
        for (int j = 0; j < 16; ++j) acc += S.attn[s][j+1] * gv[j];
        float nv = (acc > 0.f) ? acc : expm1f(acc);
        nweg[pT*(K*512) + s*512 + kbase + c] = nv;
      } else if (gi == 27) {
        const int s = t & 15;
        if (s < nA2) {
          float pp = 0.f;
          #pragma unroll
          for (int kk = 0; kk < 16; ++kk) pp += S.hev[s][kk] * S.a2[kbase + kk];
          eHpg[((v0A2+s)&63)*32 + b] = pp;
        }
      }
    }
    __syncthreads();   // sync2
    ++ep;
    if (t == 0) __hip_atomic_store(&flags[b*32], ep, __ATOMIC_RELEASE, __HIP_MEMORY_SCOPE_AGENT);
    if (t < 32) {
      while (__hip_atomic_load(&flags[t*32], __ATOMIC_RELAXED, __HIP_MEMORY_SCOPE_AGENT) < ep) { }
    }
    if (t == 0) (void)__hip_atomic_load(&flags[0], __ATOMIC_ACQUIRE, __HIP_MEMORY_SCOPE_AGENT);
    __syncthreads();

    // ---- advance ----
    if (nD > 0) d_done = v0D + nD - 1;
    va += n;
    ++T;
    if (d_done == NV-1) break;
    if (T > 12000u) break;   // safety: fail validation instead of hanging
  }

  // ================= output =================
  if (b == 0) {
    for (int i = t; i < NV; i += TPB) out[i] = (float)((int)S.colors[i] - 1);
    if (t == 0) {
      int bv = basep[0];
      int bl = (bv >= -100000 && bv <= 100000) ? bv : (int)__int_as_float(bv);
      float loss = ((float)(S.scali[0] - bl)) * S.scalf[0] / 8192.0f + 0.05f * S.scalf[1];
      out[NV] = loss;
    }
  }
}

extern "C" void kernel_launch(void* const* d_in, const int* in_sizes, int n_in,
                              void* d_out, int out_size, void* d_ws, size_t ws_size,
                              hipStream_t stream) {
  const int*   adj  = (const int*)d_in[0];
  const float* W    = (const float*)d_in[1];
  const float* av   = (const float*)d_in[2];
  const float* f1w  = (const float*)d_in[3];
  const float* f1b  = (const float*)d_in[4];
  const float* f2w  = (const float*)d_in[5];
  const float* f2b  = (const float*)d_in[6];
  const float* f3w  = (const float*)d_in[7];
  const float* f3b  = (const float*)d_in[8];
  const int*   bas  = (const int*)d_in[9];
  float* out = (float*)d_out;
  unsigned char* ws = (unsigned char*)d_ws;

  // zero barrier flags (workspace is poisoned 0xAA before every launch)
  (void)hipMemsetAsync(d_ws, 0, 8192, stream);
  (void)hipFuncSetAttribute((const void*)gc_kernel,
                      hipFuncAttributeMaxDynamicSharedMemorySize,
                      (int)sizeof(Smem));
  gc_kernel<<<dim3(GBLK), dim3(TPB), sizeof(Smem), stream>>>(
      adj, W, av, f1w, f1b, f2w, f2b, f3w, f3b, bas, out, ws);
}